// Round 14
// baseline (997.412 us; speedup 1.0000x reference)
//
#include <hip/hip_runtime.h>
#include <hip/hip_bf16.h>
#include <cstdint>

#define NROWS 262144
#define HDIM  512
#define NENT  100000
#define SCAN_NBLK ((NENT + 1023) / 1024)

typedef __attribute__((ext_vector_type(4))) float  f32x4;
typedef __attribute__((ext_vector_type(8))) short  bf16x8;
typedef __attribute__((ext_vector_type(4))) short  bf16x4;

static __device__ __forceinline__ unsigned short f2bf(float x) {
    unsigned u = __float_as_uint(x);
    u += 0x7FFF + ((u >> 16) & 1);          // round-to-nearest-even
    return (unsigned short)(u >> 16);
}
static __device__ __forceinline__ float bf2f(unsigned short h) {
    return __uint_as_float(((unsigned)h) << 16);
}

// Pack W into WeP/WsP bf16 A-frag arrays (dst[(nt*16+kt)*64+lane]) AND zero
// the counts array, in one dispatch (disjoint blockIdx ranges).
__global__ __launch_bounds__(256) void pack_zero_kernel(
    const float* __restrict__ W, unsigned short* __restrict__ WeP,
    unsigned short* __restrict__ WsP, unsigned* __restrict__ counts)
{
    int bid = blockIdx.x;
    if (bid < 256) {
        int g    = bid * 256 + threadIdx.x;   // 65536
        int sel  = g >> 15;
        int gg   = g & 32767;
        int lane = gg & 63;
        int kt   = (gg >> 6) & 15;
        int nt   = gg >> 10;
        int col  = nt * 16 + (lane & 15);
        int k    = kt * 32 + ((lane >> 4) << 3) + sel * 512;
        const float* src = W + (size_t)col * 1024 + k;
        f32x4 v0 = *(const f32x4*)(src);
        f32x4 v1 = *(const f32x4*)(src + 4);
        bf16x8 ov;
#pragma unroll
        for (int i = 0; i < 4; ++i) {
            ov[i]     = (short)f2bf(v0[i]);
            ov[4 + i] = (short)f2bf(v1[i]);
        }
        unsigned short* dst = sel ? WsP : WeP;
        *(bf16x8*)(dst + (size_t)gg * 8) = ov;
    } else {
        int i = (bid - 256) * 256 + threadIdx.x;
        if (i < NENT) counts[i] = 0u;
    }
}

// ---- CSR build ----
__global__ __launch_bounds__(1024) void scan1_kernel(const unsigned* __restrict__ counts,
                                                     unsigned* __restrict__ off,
                                                     unsigned* __restrict__ bsums) {
    __shared__ unsigned tmp[1024];
    int i = blockIdx.x * 1024 + threadIdx.x;
    unsigned v = (i < NENT) ? counts[i] : 0u;
    tmp[threadIdx.x] = v;
    __syncthreads();
#pragma unroll
    for (int o = 1; o < 1024; o <<= 1) {
        unsigned a = (threadIdx.x >= o) ? tmp[threadIdx.x - o] : 0u;
        __syncthreads();
        tmp[threadIdx.x] += a;
        __syncthreads();
    }
    if (i < NENT) off[i] = tmp[threadIdx.x] - v;     // block-local exclusive
    if (threadIdx.x == 1023) bsums[blockIdx.x] = tmp[1023];
}

__global__ void scan2_kernel(unsigned* __restrict__ bsums) {
    if (threadIdx.x == 0 && blockIdx.x == 0) {
        unsigned s = 0;
        for (int i = 0; i < SCAN_NBLK; ++i) { unsigned t = bsums[i]; bsums[i] = s; s += t; }
    }
}

__global__ __launch_bounds__(1024) void scan3_kernel(unsigned* __restrict__ off,
                                                     const unsigned* __restrict__ bsums,
                                                     unsigned* __restrict__ cursor) {
    int i = blockIdx.x * 1024 + threadIdx.x;
    if (i < NENT) {
        unsigned o = off[i] + bsums[blockIdx.x];
        off[i] = o;
        cursor[i] = o;
    }
    if (i == 0) off[NENT] = NROWS;
}

__global__ __launch_bounds__(256) void fill_kernel(const int* __restrict__ ids,
                                                   unsigned* __restrict__ cursor,
                                                   int* __restrict__ rowidx) {
    int r = blockIdx.x * 256 + threadIdx.x;
    if (r < NROWS) {
        unsigned p = atomicAdd(&cursor[ids[r]], 1u);
        rowidx[p] = r;
    }
}

// Kernel A: per-entity precompute + fused id-count. 32 entities/block,
// 512 thr = 8 waves. h = LN(slow[e]); Gs = h @ Ws.T + b. Stores h, Gs bf16.
__global__ __launch_bounds__(512, 4) void entity_kernel(
    const float* __restrict__ slow, const unsigned short* __restrict__ WsP,
    const float* __restrict__ bias, const int* __restrict__ ids,
    unsigned* __restrict__ counts, unsigned short* __restrict__ hB,
    unsigned short* __restrict__ GsB, float* __restrict__ actB)
{
    __shared__ unsigned short xLds[2048 * 8];   // 32 KB
    __shared__ float muS[32], rsS[32], bS[512];

    const int t    = threadIdx.x;
    const int w    = t >> 6;          // 0..7
    const int lane = t & 63;
    const int brow = blockIdx.x * 32;

    // fused count: first 512 blocks fire one atomic each thread
    {
        int gid = blockIdx.x * 512 + t;
        if (gid < NROWS) atomicAdd(&counts[ids[gid]], 1u);
    }

    if (t < 128) ((f32x4*)bS)[t] = ((const f32x4*)bias)[t];

    for (int rr = 0; rr < 4; ++rr) {
        int row = w * 4 + rr;
        int e   = brow + row;
        const float* sp = slow + (size_t)e * HDIM;
        f32x4 v0 = ((const f32x4*)sp)[lane * 2];
        f32x4 v1 = ((const f32x4*)sp)[lane * 2 + 1];
        float s = 0.f, s2 = 0.f, sa = 0.f;
#pragma unroll
        for (int i = 0; i < 4; ++i) {
            s  += v0[i] + v1[i];
            s2 += v0[i] * v0[i] + v1[i] * v1[i];
            sa += fabsf(v0[i]) + fabsf(v1[i]);
        }
#pragma unroll
        for (int m = 32; m >= 1; m >>= 1) {
            s  += __shfl_xor(s, m);
            s2 += __shfl_xor(s2, m);
            sa += __shfl_xor(sa, m);
        }
        if (lane == 0) {
            float mu  = s * (1.f / HDIM);
            float var = s2 * (1.f / HDIM) - mu * mu;
            muS[row] = mu;
            rsS[row] = rsqrtf(var + 1e-5f);
            actB[e]  = (sa > 1e-6f) ? 1.f : 0.f;
        }
    }
    __syncthreads();

    // stage whole K=512 as LN(slow) bf16 fragments: tile T = kt*2 + rt
#pragma unroll
    for (int i = 0; i < 4; ++i) {
        int s  = t + i * 512;
        int T  = s >> 6, ls = s & 63;
        int row = (T & 1) * 16 + (ls & 15);
        int k   = (T >> 1) * 32 + ((ls >> 4) << 3);
        const float* p = slow + (size_t)(brow + row) * HDIM + k;
        f32x4 x0 = *(const f32x4*)p, x1 = *(const f32x4*)(p + 4);
        float mu = muS[row], rs = rsS[row];
        bf16x8 av;
#pragma unroll
        for (int j = 0; j < 4; ++j) {
            av[j]     = (short)f2bf((x0[j] - mu) * rs);
            av[4 + j] = (short)f2bf((x1[j] - mu) * rs);
        }
        ((bf16x8*)xLds)[s] = av;
    }
    __syncthreads();

    f32x4 zero4 = {0.f, 0.f, 0.f, 0.f};
    f32x4 acc[2][4];
#pragma unroll
    for (int i = 0; i < 2; ++i)
#pragma unroll
        for (int j = 0; j < 4; ++j) acc[i][j] = zero4;

#define LOADW_A(dst, kt)                                                \
    {   _Pragma("unroll")                                               \
        for (int ct = 0; ct < 4; ++ct)                                  \
            dst[ct] = *(const bf16x8*)(WsP +                            \
                ((size_t)(((w * 4 + ct) * 16 + (kt)) * 64 + lane) << 3)); \
    }
#define LOADX_A(dst, kt)                                                \
    {   _Pragma("unroll")                                               \
        for (int rt = 0; rt < 2; ++rt)                                  \
            dst[rt] = ((const bf16x8*)xLds)[((kt) * 2 + rt) * 64 + lane]; \
    }
#define STEP(wf, xf)                                                    \
    {   _Pragma("unroll")                                               \
        for (int ct = 0; ct < 4; ++ct) {                                \
            acc[0][ct] = __builtin_amdgcn_mfma_f32_16x16x32_bf16(wf[ct], xf[0], acc[0][ct], 0, 0, 0); \
            acc[1][ct] = __builtin_amdgcn_mfma_f32_16x16x32_bf16(wf[ct], xf[1], acc[1][ct], 0, 0, 0); \
        }                                                               \
    }

    {
        bf16x8 wA[4], wB[4], xA[2], xB[2];
        LOADW_A(wA, 0); LOADX_A(xA, 0);
#pragma unroll
        for (int kt = 0; kt < 16; kt += 2) {
            if (kt + 1 < 16) { LOADW_A(wB, kt + 1); LOADX_A(xB, kt + 1); }
            STEP(wA, xA);
            if (kt + 2 < 16) { LOADW_A(wA, kt + 2); LOADX_A(xA, kt + 2); }
            if (kt + 1 < 16) STEP(wB, xB);
        }
    }
#undef LOADW_A
#undef LOADX_A

    // epilogue: Gs = acc + b -> bf16; h from LDS -> bf16
#pragma unroll
    for (int rt = 0; rt < 2; ++rt) {
        int e = brow + rt * 16 + (lane & 15);
#pragma unroll
        for (int ct = 0; ct < 4; ++ct) {
            int col0 = w * 64 + ct * 16 + ((lane >> 4) << 2);
            f32x4 bv = *(const f32x4*)&bS[col0];
            bf16x4 gv;
#pragma unroll
            for (int r = 0; r < 4; ++r) gv[r] = (short)f2bf(acc[rt][ct][r] + bv[r]);
            *(bf16x4*)(GsB + (size_t)e * HDIM + col0) = gv;
        }
    }
#pragma unroll
    for (int i = 0; i < 4; ++i) {
        int s  = t + i * 512;
        int T  = s >> 6, ls = s & 63;
        int row = (T & 1) * 16 + (ls & 15);
        int k   = (T >> 1) * 32 + ((ls >> 4) << 3);
        *(bf16x8*)(hB + (size_t)(brow + row) * HDIM + k) = ((const bf16x8*)xLds)[s];
    }
}

// Kernel B v4: 64 rows/block, 1024 thr = 16 waves (2M x 8N; wave = 32r x 64c).
// Split-K staging: stage K<256, barrier, issue K>=256 loads (fly under the
// first 8-kt compute), pack+write, barrier, compute kt 8..15. Epilogue: emb
// from LDS; gather Gs/h/act by id.
__global__ __launch_bounds__(1024, 4) void fuse_kernel(
    const float* __restrict__ emb, const unsigned short* __restrict__ WeP,
    const int* __restrict__ ids, const unsigned short* __restrict__ hB,
    const unsigned short* __restrict__ GsB, const float* __restrict__ actB,
    float* __restrict__ out)
{
    __shared__ unsigned short xLds[4096 * 8];   // 64 KB: tile T = kt*4 + rt
    __shared__ int idS[64];

    const int t    = threadIdx.x;
    const int w    = t >> 6;          // 0..15
    const int lane = t & 63;
    const int wm   = w >> 3;          // 0..1  row half
    const int wn   = w & 7;           // 0..7  col group
    const int brow = blockIdx.x * 64;

    if (t < 64) idS[t] = ids[brow + t];

#define XGEO(s, row, k)                                                  \
    int T_ = (s) >> 6, ls_ = (s) & 63;                                   \
    row = (T_ & 3) * 16 + (ls_ & 15);                                    \
    k   = (T_ >> 2) * 32 + ((ls_ >> 4) << 3);

#define XPACK(s, x0, x1)                                                 \
    {   bf16x8 av_;                                                      \
        _Pragma("unroll")                                                \
        for (int j = 0; j < 4; ++j) {                                    \
            av_[j]     = (short)f2bf(x0[j]);                             \
            av_[4 + j] = (short)f2bf(x1[j]);                             \
        }                                                                \
        ((bf16x8*)xLds)[s] = av_;                                        \
    }

    // ---- stage half 1 (K < 256): slots t, t+1024 ----
#pragma unroll
    for (int i = 0; i < 2; ++i) {
        int s = t + i * 1024;
        int row, k; XGEO(s, row, k);
        const float* p = emb + (size_t)(brow + row) * HDIM + k;
        f32x4 x0 = *(const f32x4*)p, x1 = *(const f32x4*)(p + 4);
        XPACK(s, x0, x1);
    }
    __syncthreads();

    // ---- issue half-2 loads (K >= 256): fly under the first 8-kt compute ----
    f32x4 h20, h21, h30, h31;
    int row2, k2, row3, k3;
    { int s = t + 2048; XGEO(s, row2, k2); }
    { int s = t + 3072; XGEO(s, row3, k3); }
    {
        const float* p2 = emb + (size_t)(brow + row2) * HDIM + k2;
        const float* p3 = emb + (size_t)(brow + row3) * HDIM + k3;
        h20 = *(const f32x4*)p2; h21 = *(const f32x4*)(p2 + 4);
        h30 = *(const f32x4*)p3; h31 = *(const f32x4*)(p3 + 4);
    }

    f32x4 zero4 = {0.f, 0.f, 0.f, 0.f};
    f32x4 acc[2][4];
#pragma unroll
    for (int i = 0; i < 2; ++i)
#pragma unroll
        for (int j = 0; j < 4; ++j) acc[i][j] = zero4;

#define LOADW_B(dst, kt)                                                \
    {   _Pragma("unroll")                                               \
        for (int ct = 0; ct < 4; ++ct)                                  \
            dst[ct] = *(const bf16x8*)(WeP +                            \
                ((size_t)(((wn * 4 + ct) * 16 + (kt)) * 64 + lane) << 3)); \
    }
#define LOADX_B(dst, kt)                                                \
    {   _Pragma("unroll")                                               \
        for (int rt = 0; rt < 2; ++rt)                                  \
            dst[rt] = ((const bf16x8*)xLds)[((kt) * 4 + wm * 2 + rt) * 64 + lane]; \
    }

    {   // compute kt 0..7 (half 1)
        bf16x8 wA[4], wB[4], xA[2], xB[2];
        LOADW_B(wA, 0); LOADX_B(xA, 0);
#pragma unroll
        for (int kt = 0; kt < 8; kt += 2) {
            LOADW_B(wB, kt + 1); LOADX_B(xB, kt + 1);
            STEP(wA, xA);
            if (kt + 2 < 8) { LOADW_B(wA, kt + 2); LOADX_B(xA, kt + 2); }
            STEP(wB, xB);
        }
    }

    // ---- pack + publish half 2 ----
    XPACK(t + 2048, h20, h21);
    XPACK(t + 3072, h30, h31);
    __syncthreads();

    {   // compute kt 8..15 (half 2)
        bf16x8 wA[4], wB[4], xA[2], xB[2];
        LOADW_B(wA, 8); LOADX_B(xA, 8);
#pragma unroll
        for (int kt = 8; kt < 16; kt += 2) {
            LOADW_B(wB, kt + 1); LOADX_B(xB, kt + 1);
            STEP(wA, xA);
            if (kt + 2 < 16) { LOADW_B(wA, kt + 2); LOADX_B(xA, kt + 2); }
            STEP(wB, xB);
        }
    }
#undef LOADW_B
#undef LOADX_B
#undef STEP
#undef XGEO
#undef XPACK

    // epilogue: z = sigmoid(acc + Gs[id]); out = act ? z*e+(1-z)*h : e
#pragma unroll
    for (int rt = 0; rt < 2; ++rt) {
        int rowl = wm * 32 + rt * 16 + (lane & 15);
        int grow = brow + rowl;
        int id   = idS[rowl];
        float act = actB[id];
        const unsigned short* gsP = GsB + (size_t)id * HDIM;
        const unsigned short* hP  = hB  + (size_t)id * HDIM;
        float* outP = out + (size_t)grow * HDIM;
#pragma unroll
        for (int ct = 0; ct < 4; ++ct) {
            int col0 = wn * 64 + ct * 16 + ((lane >> 4) << 2);
            int Te = ((col0 >> 5) * 4 + wm * 2 + rt) * 64 + (((col0 >> 3) & 3) << 4) + (lane & 15);
            const unsigned short* pe = xLds + Te * 8 + (col0 & 7);
            bf16x4 gv = *(const bf16x4*)(gsP + col0);
            bf16x4 hv = *(const bf16x4*)(hP + col0);
            f32x4 o;
#pragma unroll
            for (int r = 0; r < 4; ++r) {
                float ev = bf2f(pe[r]);
                float logit = acc[rt][ct][r] + bf2f(gv[r]);
                float z = 1.f / (1.f + __expf(-logit));
                float fused = z * ev + (1.f - z) * bf2f(hv[r]);
                o[r] = (act > 0.f) ? fused : ev;
            }
            *(f32x4*)(outP + col0) = o;
        }
    }
}

// Per-entity gather-finalize with 4-deep MLP on the out-row gather.
__global__ __launch_bounds__(256) void finalize_kernel(
    const float* __restrict__ fast, const float* __restrict__ slow,
    const float* __restrict__ out, const unsigned* __restrict__ off,
    const int* __restrict__ rowidx, float* __restrict__ nf, float* __restrict__ ns)
{
    int e = blockIdx.x * 4 + (threadIdx.x >> 6);
    if (e >= NENT) return;
    int lane = threadIdx.x & 63;
    size_t base = (size_t)e * HDIM + lane * 8;

    f32x4 f0 = *(const f32x4*)(fast + base), f1 = *(const f32x4*)(fast + base + 4);
    f32x4 l0 = *(const f32x4*)(slow + base), l1 = *(const f32x4*)(slow + base + 4);

    unsigned o0 = off[e], o1 = off[e + 1];
    int c = (int)(o1 - o0);

    if (c == 0) {
        *(f32x4*)(nf + base)     = f0;
        *(f32x4*)(nf + base + 4) = f1;
        *(f32x4*)(ns + base)     = l0;
        *(f32x4*)(ns + base + 4) = l1;
        return;
    }

    f32x4 s0 = {0.f, 0.f, 0.f, 0.f}, s1 = {0.f, 0.f, 0.f, 0.f};
    int j = (int)o0, end = (int)o1;
    while (j + 4 <= end) {
        int r0 = rowidx[j], r1 = rowidx[j + 1], r2 = rowidx[j + 2], r3 = rowidx[j + 3];
        const float* p0 = out + (size_t)r0 * HDIM + lane * 8;
        const float* p1 = out + (size_t)r1 * HDIM + lane * 8;
        const float* p2 = out + (size_t)r2 * HDIM + lane * 8;
        const float* p3 = out + (size_t)r3 * HDIM + lane * 8;
        f32x4 a0 = *(const f32x4*)p0, b0 = *(const f32x4*)(p0 + 4);
        f32x4 a1 = *(const f32x4*)p1, b1 = *(const f32x4*)(p1 + 4);
        f32x4 a2 = *(const f32x4*)p2, b2 = *(const f32x4*)(p2 + 4);
        f32x4 a3 = *(const f32x4*)p3, b3 = *(const f32x4*)(p3 + 4);
        s0 += a0 + a1 + a2 + a3;
        s1 += b0 + b1 + b2 + b3;
        j += 4;
    }
    while (j < end) {
        int r = rowidx[j++];
        const float* p = out + (size_t)r * HDIM + lane * 8;
        s0 += *(const f32x4*)p;
        s1 += *(const f32x4*)(p + 4);
    }

    float inv = 0.5f / (float)c;          // ALPHA / count
    f32x4 n0, n1, d0, d1;
    float ss = 0.f;
#pragma unroll
    for (int i = 0; i < 4; ++i) {
        n0[i] = 0.5f * f0[i] + s0[i] * inv;
        n1[i] = 0.5f * f1[i] + s1[i] * inv;
        d0[i] = n0[i] - l0[i]; ss += d0[i] * d0[i];
        d1[i] = n1[i] - l1[i]; ss += d1[i] * d1[i];
    }
#pragma unroll
    for (int m = 32; m >= 1; m >>= 1) ss += __shfl_xor(ss, m);
    float delta = sqrtf(ss);
    float gate  = 1.f / (1.f + expf(-5.f * (delta - 0.5f)));

    f32x4 o0v, o1v;
#pragma unroll
    for (int i = 0; i < 4; ++i) {
        o0v[i] = l0[i] + gate * d0[i];
        o1v[i] = l1[i] + gate * d1[i];
    }
    *(f32x4*)(nf + base)     = n0;
    *(f32x4*)(nf + base + 4) = n1;
    *(f32x4*)(ns + base)     = o0v;
    *(f32x4*)(ns + base + 4) = o1v;
}

extern "C" void kernel_launch(void* const* d_in, const int* in_sizes, int n_in,
                              void* d_out, int out_size, void* d_ws, size_t ws_size,
                              hipStream_t stream) {
    const float* emb  = (const float*)d_in[0];
    const float* slow = (const float*)d_in[1];
    const float* fast = (const float*)d_in[2];
    const float* W    = (const float*)d_in[3];
    const float* bias = (const float*)d_in[4];
    const int*   ids  = (const int*)d_in[5];

    float* out = (float*)d_out;
    float* nf  = out + (size_t)NROWS * HDIM;
    float* ns  = nf + (size_t)NENT * HDIM;

    // h/Gs (bf16) live in the nf/ns regions until finalize overwrites them.
    unsigned short* hB  = (unsigned short*)nf;
    unsigned short* GsB = (unsigned short*)ns;

    // ws: WeP 512K | WsP 512K | actB 400K | counts 400K | off 400K+4 | bsums | rowidx 1M
    unsigned short* WeP = (unsigned short*)d_ws;
    unsigned short* WsP = (unsigned short*)((char*)d_ws + (512u << 10));
    float* actB         = (float*)((char*)d_ws + (1024u << 10));
    unsigned* counts    = (unsigned*)((char*)d_ws + (1536u << 10));   // reused as cursor
    unsigned* off       = (unsigned*)((char*)d_ws + (2048u << 10));
    unsigned* bsums     = (unsigned*)((char*)d_ws + (2560u << 10));
    int*      rowidx    = (int*)((char*)d_ws + (2560u << 10) + 4096);

    pack_zero_kernel<<<256 + (NENT + 255) / 256, 256, 0, stream>>>(W, WeP, WsP, counts);
    entity_kernel<<<NENT / 32, 512, 0, stream>>>(slow, WsP, bias, ids, counts, hB, GsB, actB);
    scan1_kernel<<<SCAN_NBLK, 1024, 0, stream>>>(counts, off, bsums);
    scan2_kernel<<<1, 64, 0, stream>>>(bsums);
    scan3_kernel<<<SCAN_NBLK, 1024, 0, stream>>>(off, bsums, counts);
    fill_kernel<<<NROWS / 256, 256, 0, stream>>>(ids, counts, rowidx);
    fuse_kernel<<<NROWS / 64, 1024, 0, stream>>>(emb, WeP, ids, hB, GsB, actB, out);
    finalize_kernel<<<(NENT + 3) / 4, 256, 0, stream>>>(fast, slow, out, off, rowidx, nf, ns);
}